// Round 1
// baseline (779.126 us; speedup 1.0000x reference)
//
#include <hip/hip_runtime.h>

#define N 512
#define WAVES 16
#define BLOCK (WAVES * 64)          // 1024 threads, 16 waves
#define ROWS_PER_WAVE (N / WAVES)   // 32

// One workgroup per 512x512 matrix. log_s = a - u_i - v_j throughout.
// Each pass fuses one (row-normalize, col-normalize) iteration pair:
//   u_i = LSE_j(a_ij - v_j)   (computed per row, one wave per row)
//   v_j = log( sum_i exp(a_ij - u_i) )   accumulated as rows finish:
//         exp(a_ij - u_i) = E_ij * exp(v_j) / S_i  with E_ij = exp(a_ij - v_j)
__global__ __launch_bounds__(BLOCK, 1)
void sinkhorn_kernel(const float* __restrict__ A, float* __restrict__ Out) {
    __shared__ float sv[N];              // v_j
    __shared__ float sev[N];             // exp(v_j)
    __shared__ float su[N];              // u_i (kept for final output pass)
    __shared__ float spart[WAVES][N];    // per-wave column-sum partials (32 KiB)

    const float* __restrict__ Ab = A + (size_t)blockIdx.x * N * N;
    float* __restrict__ Ob       = Out + (size_t)blockIdx.x * N * N;
    const int tid  = threadIdx.x;
    const int lane = tid & 63;
    const int wave = tid >> 6;

    if (tid < N) { sv[tid] = 0.0f; sev[tid] = 1.0f; }
    __syncthreads();

    for (int pass = 0; pass < 10; ++pass) {
        // hoist this wave's column slice of v and exp(v) (loop-invariant)
        const float4 v0  = ((const float4*)sv)[lane];
        const float4 v1  = ((const float4*)sv)[lane + 64];
        const float4 ev0 = ((const float4*)sev)[lane];
        const float4 ev1 = ((const float4*)sev)[lane + 64];
        float t0=0.f,t1=0.f,t2=0.f,t3=0.f,t4=0.f,t5=0.f,t6=0.f,t7=0.f;

        #pragma unroll 2
        for (int k = 0; k < ROWS_PER_WAVE; ++k) {
            const int row = k * WAVES + wave;   // strided: waves sweep a moving 32KiB window
            const float4* R = (const float4*)(Ab + (size_t)row * N);
            const float4 x0 = R[lane];
            const float4 x1 = R[lane + 64];

            const float e0 = __expf(x0.x - v0.x);
            const float e1 = __expf(x0.y - v0.y);
            const float e2 = __expf(x0.z - v0.z);
            const float e3 = __expf(x0.w - v0.w);
            const float e4 = __expf(x1.x - v1.x);
            const float e5 = __expf(x1.y - v1.y);
            const float e6 = __expf(x1.z - v1.z);
            const float e7 = __expf(x1.w - v1.w);

            float S = ((e0 + e1) + (e2 + e3)) + ((e4 + e5) + (e6 + e7));
            #pragma unroll
            for (int m = 1; m < 64; m <<= 1) S += __shfl_xor(S, m, 64);

            if (lane == 0) su[row] = __logf(S);   // u_i; last pass's value feeds output
            const float inv = 1.0f / S;

            t0 += e0 * ev0.x * inv;
            t1 += e1 * ev0.y * inv;
            t2 += e2 * ev0.z * inv;
            t3 += e3 * ev0.w * inv;
            t4 += e4 * ev1.x * inv;
            t5 += e5 * ev1.y * inv;
            t6 += e6 * ev1.z * inv;
            t7 += e7 * ev1.w * inv;
        }

        // stage per-wave partials (conflict-free b128 writes), then tree-reduce
        ((float4*)spart[wave])[lane]      = make_float4(t0, t1, t2, t3);
        ((float4*)spart[wave])[lane + 64] = make_float4(t4, t5, t6, t7);
        __syncthreads();

        if (tid < N) {
            float s = 0.f;
            #pragma unroll
            for (int w = 0; w < WAVES; ++w) s += spart[w][tid];
            sev[tid] = s;           // exp(v_j) = column sum directly (no exp needed)
            sv[tid]  = __logf(s);
        }
        __syncthreads();
    }

    // output pass: out_ij = exp(a_ij - u_i - v_j)
    const float4 v0 = ((const float4*)sv)[lane];
    const float4 v1 = ((const float4*)sv)[lane + 64];
    #pragma unroll 2
    for (int k = 0; k < ROWS_PER_WAVE; ++k) {
        const int row = k * WAVES + wave;
        const float4* R = (const float4*)(Ab + (size_t)row * N);
        float4* W       = (float4*)(Ob + (size_t)row * N);
        const float4 x0 = R[lane];
        const float4 x1 = R[lane + 64];
        const float ui  = su[row];

        float4 o0, o1;
        o0.x = __expf(x0.x - ui - v0.x);
        o0.y = __expf(x0.y - ui - v0.y);
        o0.z = __expf(x0.z - ui - v0.z);
        o0.w = __expf(x0.w - ui - v0.w);
        o1.x = __expf(x1.x - ui - v1.x);
        o1.y = __expf(x1.y - ui - v1.y);
        o1.z = __expf(x1.z - ui - v1.z);
        o1.w = __expf(x1.w - ui - v1.w);

        W[lane]      = o0;
        W[lane + 64] = o1;
    }
}

extern "C" void kernel_launch(void* const* d_in, const int* in_sizes, int n_in,
                              void* d_out, int out_size, void* d_ws, size_t ws_size,
                              hipStream_t stream) {
    const float* s = (const float*)d_in[0];
    float* out = (float*)d_out;
    const int nmat = in_sizes[0] / (N * N);   // 256
    sinkhorn_kernel<<<nmat, BLOCK, 0, stream>>>(s, out);
}